// Round 6
// baseline (164.107 us; speedup 1.0000x reference)
//
#include <hip/hip_runtime.h>
#include <hip/hip_bf16.h>
#include <stdint.h>

// Problem dims (fixed)
#define MD    1024      // model dim
#define NHEAD 16
#define HDIM  64
#define BSZ   2
#define SEQL  2048
#define MROWS 4096      // BSZ*SEQL

#define SCL2E 0.18033688011112042f   // (1/sqrt(64)) * log2(e), folded into Wq/bq

typedef __bf16 bf16_t;
typedef __bf16  bf16x8 __attribute__((ext_vector_type(8)));
typedef float   f32x4  __attribute__((ext_vector_type(4)));
typedef short   short8 __attribute__((ext_vector_type(8)));

// Async global->LDS, 16B per lane. LDS dest is wave-uniform base (+lane*16 by HW).
__device__ __forceinline__ void gload_lds16(const void* g, void* l) {
  __builtin_amdgcn_global_load_lds((const __attribute__((address_space(1))) void*)g,
                                   (__attribute__((address_space(3))) void*)l,
                                   16, 0, 0);
}

__device__ __forceinline__ unsigned short f2bf(float f) {
  unsigned u = __builtin_bit_cast(unsigned, f);
  u += 0x7fffu + ((u >> 16) & 1u);          // round-to-nearest-even
  return (unsigned short)(u >> 16);
}

// packed 2xf32 -> 2xbf16 in one dword (src0 -> low half)
__device__ __forceinline__ unsigned cvtpk(float a, float b) {
  unsigned r;
  asm("v_cvt_pk_bf16_f32 %0, %1, %2" : "=v"(r) : "v"(a), "v"(b));
  return r;
}

// ---------------- consolidated convert ----------------
// grid 16387: [0,12288) X (4096 each), [12288,16384) W (1024 each; Wq scaled),
// 16384: bq*SCL2E -> bqs ; 16385/16386: nmask[b] = sum(1-mask[b][:])
__global__ __launch_bounds__(256)
void cvt_all(const float* __restrict__ q, const float* __restrict__ k, const float* __restrict__ v,
             const float* __restrict__ wq, const float* __restrict__ wk,
             const float* __restrict__ wv, const float* __restrict__ wo,
             const float* __restrict__ mask, const float* __restrict__ bq,
             unsigned short* __restrict__ xq, unsigned short* __restrict__ xk, unsigned short* __restrict__ xv,
             unsigned short* __restrict__ wqb, unsigned short* __restrict__ wkb,
             unsigned short* __restrict__ wvb, unsigned short* __restrict__ wob,
             float* __restrict__ bqs, float* __restrict__ nmask) {
  int bx = blockIdx.x;
  if (bx >= 16384) {
    if (bx == 16384) {                    // bqs = bq * SCL2E (1024 floats)
      int i = threadIdx.x;
      float4 val = ((const float4*)bq)[i];
      float4 o;
      o.x = val.x * SCL2E; o.y = val.y * SCL2E; o.z = val.z * SCL2E; o.w = val.w * SCL2E;
      ((float4*)bqs)[i] = o;
    } else {                              // nmask[b]
      int b = bx - 16385;
      const float* mp = mask + b * SEQL + threadIdx.x * 8;
      float s = 0.0f;
#pragma unroll
      for (int j = 0; j < 8; ++j) s += 1.0f - mp[j];
      for (int d = 1; d < 64; d <<= 1) s += __shfl_xor(s, d);
      __shared__ float wsum[4];
      if ((threadIdx.x & 63) == 0) wsum[threadIdx.x >> 6] = s;
      __syncthreads();
      if (threadIdx.x == 0) nmask[b] = wsum[0] + wsum[1] + wsum[2] + wsum[3];
    }
    return;
  }
  const float* in; unsigned short* out; int i;
  float scale = 1.0f;
  if (bx < 12288) {
    int t = bx >> 12;
    in  = (t == 0) ? q : (t == 1) ? k : v;
    out = (t == 0) ? xq : (t == 1) ? xk : xv;
    i = (bx & 4095) * 256 + threadIdx.x;
  } else {
    int t = (bx - 12288) >> 10;
    in  = (t == 0) ? wq : (t == 1) ? wk : (t == 2) ? wv : wo;
    out = (t == 0) ? wqb : (t == 1) ? wkb : (t == 2) ? wvb : wob;
    if (t == 0) scale = SCL2E;
    i = (bx & 1023) * 256 + threadIdx.x;
  }
  float4 val = ((const float4*)in)[i];
  ushort4 o;
  o.x = f2bf(val.x * scale); o.y = f2bf(val.y * scale);
  o.z = f2bf(val.z * scale); o.w = f2bf(val.w * scale);
  ((ushort4*)out)[i] = o;
}

// ---------------- GEMM: C[m,n] = sum_k A[m,k]*B[n,k] + bias[n] ----------------
// 128x128 tile, BK=64, 4 waves (2x2 of 64x64), 16x16x32 bf16 MFMA.
// LDS tiles [128 rows][128 bytes], XOR-swizzled via pre-swizzled global source.
// MODE: 0 = bf16 row-major [m][n]; 1 = f32 row-major;
//       2 = bf16 V^T layout Vt[(b*1024+n)*2048+s], row-masked;
//       3 = bf16 row-major, row-masked (K projection).
template<int MODE>
__device__ __forceinline__ void gemm_body(const bf16_t* __restrict__ A,
                                          const bf16_t* __restrict__ Bm,
                                          const float*  __restrict__ bias,
                                          const float*  __restrict__ mask,
                                          void* __restrict__ Cout, int tile) {
  __shared__ __align__(1024) char sm[32768];
  char* lsA = sm;
  char* lsB = sm + 16384;
  const int tid  = threadIdx.x;
  const int lane = tid & 63;
  const int wv   = tid >> 6;
  const int wm   = wv >> 1, wn = wv & 1;
  const int m0   = (tile >> 3) << 7;   // 32 m-tiles
  const int n0   = (tile & 7)  << 7;   // 8 n-tiles
  const int l15  = lane & 15;
  const int g16  = (lane >> 4) << 4;   // k-group byte base

  f32x4 acc[4][4] = {};

  for (int kk = 0; kk < MD; kk += 64) {
#pragma unroll
    for (int i = 0; i < 4; ++i) {
      int ch  = (wv << 2) + i;
      int o   = ch * 1024 + (lane << 4);
      int row = o >> 7;
      int scb = (o & 127) ^ ((row & 7) << 4);   // pre-swizzled source column byte
      const char* gA = (const char*)A  + (((size_t)(m0 + row) * MD + kk) << 1) + scb;
      const char* gB = (const char*)Bm + (((size_t)(n0 + row) * MD + kk) << 1) + scb;
      gload_lds16(gA, lsA + ch * 1024);
      gload_lds16(gB, lsB + ch * 1024);
    }
    __syncthreads();
#pragma unroll
    for (int s = 0; s < 2; ++s) {
      bf16x8 af[4], bfv[4];
#pragma unroll
      for (int mi = 0; mi < 4; ++mi) {
        int r  = (wm << 6) + (mi << 4) + l15;
        int cb = (g16 + (s << 6)) ^ ((r & 7) << 4);
        af[mi] = *(const bf16x8*)(lsA + (r << 7) + cb);
      }
#pragma unroll
      for (int ni = 0; ni < 4; ++ni) {
        int r  = (wn << 6) + (ni << 4) + l15;
        int cb = (g16 + (s << 6)) ^ ((r & 7) << 4);
        bfv[ni] = *(const bf16x8*)(lsB + (r << 7) + cb);
      }
      __builtin_amdgcn_s_setprio(1);
#pragma unroll
      for (int mi = 0; mi < 4; ++mi)
#pragma unroll
        for (int ni = 0; ni < 4; ++ni)
          acc[mi][ni] = __builtin_amdgcn_mfma_f32_16x16x32_bf16(af[mi], bfv[ni], acc[mi][ni], 0, 0, 0);
      __builtin_amdgcn_s_setprio(0);
    }
    __syncthreads();
  }

  // epilogue: C/D layout col = lane&15, row = (lane>>4)*4 + reg
  float bvv[4];
#pragma unroll
  for (int ni = 0; ni < 4; ++ni) bvv[ni] = bias[n0 + (wn << 6) + (ni << 4) + l15];
#pragma unroll
  for (int mi = 0; mi < 4; ++mi) {
    int m = m0 + (wm << 6) + (mi << 4) + ((lane >> 4) << 2);  // token rows m..m+3
    float4 mk = {1.0f, 1.0f, 1.0f, 1.0f};
    if constexpr (MODE == 2 || MODE == 3) mk = *(const float4*)&mask[m];
#pragma unroll
    for (int ni = 0; ni < 4; ++ni) {
      int col = n0 + (wn << 6) + (ni << 4) + l15;
      if constexpr (MODE == 2) {
        int bb = m >> 11;
        int s  = m & 2047;
        ushort4 pk;
        pk.x = f2bf((acc[mi][ni][0] + bvv[ni]) * mk.x);
        pk.y = f2bf((acc[mi][ni][1] + bvv[ni]) * mk.y);
        pk.z = f2bf((acc[mi][ni][2] + bvv[ni]) * mk.z);
        pk.w = f2bf((acc[mi][ni][3] + bvv[ni]) * mk.w);
        *(ushort4*)((unsigned short*)Cout + ((size_t)(bb << 10) + col) * SEQL + s) = pk;
      } else {
#pragma unroll
        for (int r = 0; r < 4; ++r) {
          float vv = acc[mi][ni][r] + bvv[ni];
          if constexpr (MODE == 3) vv *= ((const float*)&mk)[r];
          if constexpr (MODE == 1) ((float*)Cout)[(size_t)(m + r) * MD + col] = vv;
          else                     ((bf16_t*)Cout)[(size_t)(m + r) * MD + col] = (bf16_t)vv;
        }
      }
    }
  }
}

// fused QKV: 768 blocks (XCD-chunked swizzle); g selects (X,W,bias,Out).
// Q pre-scaled (bqs), K row-masked, V transposed + row-masked.
__global__ __launch_bounds__(256, 2)
void gemm_qkv(const bf16_t* __restrict__ xq, const bf16_t* __restrict__ xk, const bf16_t* __restrict__ xv,
              const bf16_t* __restrict__ wq, const bf16_t* __restrict__ wk, const bf16_t* __restrict__ wv_,
              const float* __restrict__ bqs, const float* __restrict__ bk, const float* __restrict__ bv,
              const float* __restrict__ mask,
              bf16_t* __restrict__ Qo, bf16_t* __restrict__ Ko, bf16_t* __restrict__ Vto) {
  int bid = (int)blockIdx.x;
  int lb  = (bid & 7) * 96 + (bid >> 3);   // 768 = 8 x 96, bijective
  int t = lb & 255;
  int g = lb >> 8;
  if (g == 0)      gemm_body<0>(xq, wq,  bqs, nullptr, Qo,  t);
  else if (g == 1) gemm_body<3>(xk, wk,  bk,  mask,    Ko,  t);
  else             gemm_body<2>(xv, wv_, bv,  mask,    Vto, t);
}

__global__ __launch_bounds__(256, 2)
void gemm_out(const bf16_t* __restrict__ A, const bf16_t* __restrict__ Bm,
              const float* __restrict__ bias, float* __restrict__ C) {
  int bid = (int)blockIdx.x;
  int lb  = (bid & 7) * 32 + (bid >> 3);   // 256 = 8 x 32
  gemm_body<1>(A, Bm, bias, nullptr, C, lb);
}

// ---------------- flash attention ----------------
// grid: 512 = b(2)*h(16)*qtile(16), XCD-chunked swizzle; block 256 = 4 waves.
// Each wave: 32 q rows (2 q-frags of 16) -> K/V LDS reads amortize 2x.
// Scale folded into Q; mask folded into K/V rows (binary mask); denominator
// corrected by nmask[b] after the loop. No per-tile mask/scale VALU at all.
// K and V^T staged via global_load_lds (swizzled source), double-buffered,
// ONE barrier per KV tile. S^T = mfma(K,Q): lane&15 = q col, rows = kv.
__global__ __launch_bounds__(256, 2)
void attn_kernel(const bf16_t* __restrict__ Q, const bf16_t* __restrict__ K,
                 const bf16_t* __restrict__ Vt, const float* __restrict__ nmask,
                 bf16_t* __restrict__ O) {
  __shared__ __align__(1024) char sK[2][8192];
  __shared__ __align__(1024) char sVT[2][8192];
  __shared__ __align__(1024) char sPt[16384];
  int bid = (int)blockIdx.x;
  int lb  = (bid & 7) * 64 + (bid >> 3);   // 512 = 8 x 64
  const int tid  = threadIdx.x;
  const int lane = tid & 63;
  const int wv   = tid >> 6;
  const int qt   = lb & 15;
  const int h    = (lb >> 4) & 15;
  const int b    = lb >> 8;
  const int q0   = qt << 7;
  const int l15  = lane & 15;
  const int lg   = lane >> 4;

  // Q fragments (B-operand): frag c rows q0+wv*32+c*16; lane q col = l15, d = lg*8+j (+32*s)
  bf16x8 qa[2][2];
#pragma unroll
  for (int c = 0; c < 2; ++c) {
    const bf16_t* qp = Q + (size_t)(b * SEQL + q0 + (wv << 5) + (c << 4) + l15) * MD + h * HDIM + (lg << 3);
    qa[c][0] = *(const bf16x8*)qp;
    qa[c][1] = *(const bf16x8*)(qp + 32);
  }

  // staging addresses (per thread): 2 chunks each for K and V^T
  const int ch0  = wv << 1;
  const int o0   = ch0 * 1024 + (lane << 4);
  const int row0 = o0 >> 7;
  const int scb0 = (o0 & 127) ^ ((row0 & 7) << 4);
  const int row1 = row0 + 8;
  const int scb1 = (o0 & 127) ^ ((row1 & 7) << 4);
  const char* Kbase  = (const char*)K  + (((size_t)(b * SEQL) * MD + h * HDIM) << 1);
  const char* VtBase = (const char*)Vt + (((size_t)((b << 10) + (h << 6)) * SEQL) << 1);

  f32x4 oacc[2][4] = {};
  float lrun[2] = {0.0f, 0.0f};
  char* sPtW = sPt + (wv << 12);           // 4KB per wave (32 rows x 128B)

  auto stage = [&](int kv0, int bsel) {
    gload_lds16(Kbase + (((size_t)(kv0 + row0) * MD) << 1) + scb0, sK[bsel] + ch0 * 1024);
    gload_lds16(Kbase + (((size_t)(kv0 + row1) * MD) << 1) + scb1, sK[bsel] + ch0 * 1024 + 1024);
    gload_lds16(VtBase + (((size_t)row0 * SEQL + kv0) << 1) + scb0, sVT[bsel] + ch0 * 1024);
    gload_lds16(VtBase + (((size_t)row1 * SEQL + kv0) << 1) + scb1, sVT[bsel] + ch0 * 1024 + 1024);
  };

  stage(0, 0);
  __syncthreads();

  for (int t = 0; t < SEQL / 64; ++t) {
    const int bsel = t & 1;
    if (t + 1 < SEQL / 64) stage((t + 1) << 6, bsel ^ 1);

    const char* kb  = sK[bsel];
    const char* vtb = sVT[bsel];

    // --- S^T = K . Q^T : rows = kv, cols = q ---
    f32x4 sacc[2][4] = {};
#pragma unroll
    for (int s = 0; s < 2; ++s) {
      bf16x8 ka[4];
#pragma unroll
      for (int f = 0; f < 4; ++f) {
        int r  = (f << 4) + l15;
        int cb = ((lg << 4) + (s << 6)) ^ ((r & 7) << 4);
        ka[f] = *(const bf16x8*)(kb + (r << 7) + cb);
      }
      __builtin_amdgcn_s_setprio(1);
#pragma unroll
      for (int f = 0; f < 4; ++f)
#pragma unroll
        for (int c = 0; c < 2; ++c)
          sacc[c][f] = __builtin_amdgcn_mfma_f32_16x16x32_bf16(ka[f], qa[c][s], sacc[c][f], 0, 0, 0);
      __builtin_amdgcn_s_setprio(0);
    }

    // --- p = exp2(z) (scale pre-folded, masked K rows give z=0 -> p=1,
    //     cancelled by zeroed V rows + nmask denominator fix) ---
#pragma unroll
    for (int c = 0; c < 2; ++c) {
      int prow = (c << 4) + l15;
      char* pbase = sPtW + (prow << 7);
      int swz = (prow & 7) << 4;
#pragma unroll
      for (int f = 0; f < 4; ++f) {
        float p0 = exp2f(sacc[c][f][0]);
        float p1 = exp2f(sacc[c][f][1]);
        float p2 = exp2f(sacc[c][f][2]);
        float p3 = exp2f(sacc[c][f][3]);
        lrun[c] += (p0 + p1) + (p2 + p3);
        uint2 pk2;
        pk2.x = cvtpk(p0, p1);
        pk2.y = cvtpk(p2, p3);
        int boff = ((f << 5) + (lg << 3)) ^ swz;
        *(uint2*)(pbase + boff) = pk2;
      }
    }

    // --- PV: O[q][d] += Pt[q][kv] * Vt[d][kv]^T ---
#pragma unroll
    for (int s = 0; s < 2; ++s) {
      int cb = (lg << 4) + (s << 6);
      bf16x8 pa[2];
#pragma unroll
      for (int c = 0; c < 2; ++c) {
        int prow = (c << 4) + l15;
        pa[c] = *(const bf16x8*)(sPtW + (prow << 7) + (cb ^ ((prow & 7) << 4)));
      }
      bf16x8 vb[4];
#pragma unroll
      for (int df = 0; df < 4; ++df) {
        int d = (df << 4) + l15;
        vb[df] = *(const bf16x8*)(vtb + (d << 7) + (cb ^ ((d & 7) << 4)));
      }
      __builtin_amdgcn_s_setprio(1);
#pragma unroll
      for (int df = 0; df < 4; ++df)
#pragma unroll
        for (int c = 0; c < 2; ++c)
          oacc[c][df] = __builtin_amdgcn_mfma_f32_16x16x32_bf16(pa[c], vb[df], oacc[c][df], 0, 0, 0);
      __builtin_amdgcn_s_setprio(0);
    }
    __syncthreads();
  }

  // denominators: cross-lane reduce, subtract masked-count correction
  float nm = nmask[b];
#pragma unroll
  for (int c = 0; c < 2; ++c) {
    float l = lrun[c];
    l += __shfl_xor(l, 16);
    l += __shfl_xor(l, 32);
    float linv = 1.0f / (l - nm);
#pragma unroll
    for (int r = 0; r < 4; ++r) {
      float lr = __shfl(linv, (lg << 2) + r);
      int row = b * SEQL + q0 + (wv << 5) + (c << 4) + (lg << 2) + r;
#pragma unroll
      for (int df = 0; df < 4; ++df)
        O[(size_t)row * MD + h * HDIM + (df << 4) + l15] = (bf16_t)(oacc[c][df][r] * lr);
    }
  }
}

// ---------------- launch ----------------
extern "C" void kernel_launch(void* const* d_in, const int* in_sizes, int n_in,
                              void* d_out, int out_size, void* d_ws, size_t ws_size,
                              hipStream_t stream) {
  const float* in_k = (const float*)d_in[0];
  const float* in_q = (const float*)d_in[1];
  const float* in_v = (const float*)d_in[2];
  const float* mask = (const float*)d_in[3];
  const float* Wq   = (const float*)d_in[4];
  const float* bq   = (const float*)d_in[5];
  const float* Wk   = (const float*)d_in[6];
  const float* bk   = (const float*)d_in[7];
  const float* Wv   = (const float*)d_in[8];
  const float* bv   = (const float*)d_in[9];
  const float* Wo   = (const float*)d_in[10];
  const float* bo   = (const float*)d_in[11];

  const size_t XN = (size_t)MROWS * MD;   // 4,194,304 elems
  const size_t WN = (size_t)MD * MD;      // 1,048,576 elems
  char* w = (char*)d_ws;
  size_t off = 0;
  auto alloc = [&](size_t bytes) { char* p = w + off; off += bytes; return p; };
  bf16_t* xq    = (bf16_t*)alloc(XN * 2);
  bf16_t* xk    = (bf16_t*)alloc(XN * 2);
  bf16_t* xv    = (bf16_t*)alloc(XN * 2);
  bf16_t* wqb   = (bf16_t*)alloc(WN * 2);
  bf16_t* wkb   = (bf16_t*)alloc(WN * 2);
  bf16_t* wvb   = (bf16_t*)alloc(WN * 2);
  bf16_t* wob   = (bf16_t*)alloc(WN * 2);
  bf16_t* Qp    = (bf16_t*)alloc(XN * 2);
  bf16_t* Kp    = (bf16_t*)alloc(XN * 2);
  bf16_t* Vtp   = (bf16_t*)alloc(XN * 2);  // V^T: [b][h][d][s]
  float*  bqs   = (float*)alloc(MD * 4);
  float*  nmask = (float*)alloc(16);
  bf16_t* attn  = xq;  // alias: xq is dead after gemm_qkv
  (void)ws_size;

  // single consolidated convert (3 X + 4 W + bqs + nmask)
  cvt_all<<<16387, 256, 0, stream>>>(in_q, in_k, in_v, Wq, Wk, Wv, Wo, mask, bq,
                                     (unsigned short*)xq, (unsigned short*)xk, (unsigned short*)xv,
                                     (unsigned short*)wqb, (unsigned short*)wkb,
                                     (unsigned short*)wvb, (unsigned short*)wob, bqs, nmask);

  // fused QKV projection; Q pre-scaled, K masked, V transposed+masked
  gemm_qkv<<<768, 256, 0, stream>>>(xq, xk, xv, wqb, wkb, wvb, bqs, bk, bv, mask, Qp, Kp, Vtp);

  // flash attention: 512 blocks x 128 q rows
  attn_kernel<<<512, 256, 0, stream>>>(Qp, Kp, Vtp, nmask, attn);

  // output projection -> fp32 d_out
  gemm_out<<<256, 256, 0, stream>>>(attn, wob, bo, (float*)d_out);
}